// Round 7
// baseline (651.160 us; speedup 1.0000x reference)
//
#include <hip/hip_runtime.h>
#include <math.h>

#define NN 50000     // nodes
#define NE 650000    // edges (without self loops)
#define NET 700000   // NE + NN self loops
#define NETP (NET + 16)
#define FD 256       // H*C = 4*64
#define NEG 0.2f
#define NB 49        // scan blocks = ceil(NN/1024)

static __device__ __forceinline__ float lrelu(float v){ return v > 0.f ? v : NEG*v; }

// bf16 helpers
static __device__ __forceinline__ unsigned short f2bf(float f){
  union { float f; unsigned u; } v; v.f = f;
  unsigned r = v.u + 0x7fff + ((v.u >> 16) & 1);
  return (unsigned short)(r >> 16);
}
static __device__ __forceinline__ float bf2f(unsigned short h){
  union { unsigned u; float f; } v; v.u = ((unsigned)h) << 16;
  return v.f;
}
static __device__ __forceinline__ float bflo(unsigned u){ return __uint_as_float(u << 16); }
static __device__ __forceinline__ float bfhi(unsigned u){ return __uint_as_float(u & 0xffff0000u); }

// async global->LDS DMA, 16 B per lane, LDS dest = uniform base + lane*16 (m97/m104)
static __device__ __forceinline__ void gload_lds16(const unsigned short* g, unsigned short* l){
  __builtin_amdgcn_global_load_lds(
      (const __attribute__((address_space(1))) unsigned int*)(g),
      (__attribute__((address_space(3))) unsigned int*)(l), 16, 0, 0);
}

typedef __attribute__((ext_vector_type(8))) short short8_t;  // 8 bf16 = 4 VGPR
typedef __attribute__((ext_vector_type(4))) float f32x4;

// ---------------- fused init: cast x/W1/W2 + degree count (disjoint block ranges) ----
#define NX (NN*128)
#define CAST_ELEMS (NX + 128*256 + 256*256)
#define CAST_BLOCKS ((CAST_ELEMS/4 + 255)/256)
#define CNT_BLOCKS ((NET + 255)/256)
__global__ void init_fused(const float* __restrict__ x, const float* __restrict__ W1,
                           const float* __restrict__ W2,
                           unsigned short* __restrict__ xh, unsigned short* __restrict__ xl,
                           unsigned short* __restrict__ bt1h, unsigned short* __restrict__ bt1l,
                           unsigned short* __restrict__ bt2h, unsigned short* __restrict__ bt2l,
                           const int* __restrict__ ei, int* __restrict__ deg){
  int b = blockIdx.x;
  if (b >= CAST_BLOCKS){
    int e = (b - CAST_BLOCKS)*256 + threadIdx.x;
    if (e < NET){
      int d = (e < NE) ? ei[NE + e] : (e - NE);
      atomicAdd(&deg[d], 1);
    }
    return;
  }
  int i = (b*256 + threadIdx.x)*4;
  if (i < NX){
    float4 f = *(const float4*)(x + i);
    ushort4 h, l;
    h.x = f2bf(f.x); l.x = f2bf(f.x - bf2f(h.x));
    h.y = f2bf(f.y); l.y = f2bf(f.y - bf2f(h.y));
    h.z = f2bf(f.z); l.z = f2bf(f.z - bf2f(h.z));
    h.w = f2bf(f.w); l.w = f2bf(f.w - bf2f(h.w));
    *(ushort4*)(xh + i) = h;
    *(ushort4*)(xl + i) = l;
    return;
  }
  int e, K;
  const float* B;
  unsigned short *bh, *bl;
  if (i < NX + 128*256){ e = i - NX; K = 128; B = W1; bh = bt1h; bl = bt1l; }
  else if (i < CAST_ELEMS){ e = i - NX - 128*256; K = 256; B = W2; bh = bt2h; bl = bt2l; }
  else return;
  int k = e >> 8, n = e & 255;
  float4 f = *(const float4*)(B + e);
  #pragma unroll
  for (int j=0;j<4;j++){
    float fv = (j==0)?f.x:(j==1)?f.y:(j==2)?f.z:f.w;
    unsigned short h = f2bf(fv);
    bh[(n+j)*K + k] = h;
    bl[(n+j)*K + k] = f2bf(fv - bf2f(h));
  }
}

// ---------------- CSR scan (parallel: 49 blocks, then 196 blocks) ----------------
__global__ void scan_block(const int* __restrict__ deg, int* __restrict__ excl, int* __restrict__ bsums){
  __shared__ int sh[256];
  int t = threadIdx.x;
  int i0 = blockIdx.x*1024 + t*4;
  int v0 = (i0+0 < NN) ? deg[i0+0] : 0;
  int v1 = (i0+1 < NN) ? deg[i0+1] : 0;
  int v2 = (i0+2 < NN) ? deg[i0+2] : 0;
  int v3 = (i0+3 < NN) ? deg[i0+3] : 0;
  int tot = v0+v1+v2+v3;
  sh[t] = tot;
  __syncthreads();
  for (int off=1; off<256; off<<=1){
    int x = (t>=off) ? sh[t-off] : 0;
    __syncthreads();
    sh[t] += x;
    __syncthreads();
  }
  int base = sh[t] - tot;
  if (i0+0 < NN) excl[i0+0] = base;
  if (i0+1 < NN) excl[i0+1] = base + v0;
  if (i0+2 < NN) excl[i0+2] = base + v0+v1;
  if (i0+3 < NN) excl[i0+3] = base + v0+v1+v2;
  if (t == 255) bsums[blockIdx.x] = sh[255];
}

__global__ void scan_add(int* __restrict__ indptr, const int* __restrict__ bsums, int* __restrict__ cursor){
  __shared__ int boff[64];
  if (threadIdx.x < 64){
    int lane = threadIdx.x;
    int v = (lane < NB) ? bsums[lane] : 0;
    int orig = v;
    for (int off=1; off<64; off<<=1){
      int u = __shfl_up(v, off);
      if (lane >= off) v += u;
    }
    boff[lane] = v - orig;   // exclusive
  }
  __syncthreads();
  int i = blockIdx.x*blockDim.x + threadIdx.x;
  if (i < NN){
    int v = indptr[i] + boff[i>>10];
    indptr[i] = v;
    cursor[i] = v;
  }
  if (i == 0) indptr[NN] = NET;
}

// scatter also records the destination per CSR slot (for the edge-parallel alpha kernel)
__global__ void scatter_csr(const int* __restrict__ ei, int* __restrict__ cursor,
                            int* __restrict__ csr, int* __restrict__ csrd){
  int e = blockIdx.x*blockDim.x + threadIdx.x;
  if (e >= NET) return;
  int s, d;
  if (e < NE){ s = ei[e]; d = ei[NE+e]; } else { s = e-NE; d = e-NE; }
  int pos = atomicAdd(&cursor[d], 1);
  csr[pos] = s;
  csrd[pos] = d;
}

// ---------------- edge-parallel alpha precompute --------------------------------
// e[h][pos] = exp(lrelu(a_src.h[src] + a_dst.h[dst])), head-major f32 [4][NETP].
// Removes exp/lrelu/al-gathers from the agg inner loop (R6 lesson: per-group
// duplicated alpha + random al reads broke both VALU budget and L2 residency).
__global__ __launch_bounds__(256) void alpha_k(const int* __restrict__ csr, const int* __restrict__ csrd,
                                               const float* __restrict__ al, float* __restrict__ eb4){
  int p = blockIdx.x*256 + threadIdx.x;
  if (p >= NET) return;
  int s = csr[p], d = csrd[p];
  float4 as = *(const float4*)(al + s*8);
  float4 ad = *(const float4*)(al + d*8 + 4);
  eb4[0*NETP + p] = __expf(lrelu(as.x + ad.x));
  eb4[1*NETP + p] = __expf(lrelu(as.y + ad.y));
  eb4[2*NETP + p] = __expf(lrelu(as.z + ad.z));
  eb4[3*NETP + p] = __expf(lrelu(as.w + ad.w));
}

// ---------------- split-bf16 MFMA GEMM (R10-proven config), pipelined DMA ----
// Output layouts:
//   Cb: group-major [8][NN][32] bf16  (group = ch>>5; 3.2 MB slice per XCD L2)
//   al: node-major  [NN][8]  f32      (cols 0-3 = a_src·h per head, 4-7 = a_dst·h)
template<int K>
__global__ __launch_bounds__(256, 3) void gemm_mfma(const unsigned short* __restrict__ Ahg,
                                                    const unsigned short* __restrict__ Alg,
                                                    const unsigned short* __restrict__ Bth,
                                                    const unsigned short* __restrict__ Btl,
                                                    unsigned short* __restrict__ Cb,
                                                    const float* __restrict__ a_src,
                                                    const float* __restrict__ a_dst,
                                                    float* __restrict__ al,
                                                    int M){
  constexpr int ITERS = K/32;
  __shared__ unsigned short Ah[128*32], Al[128*32], Bh[128*32], Bl[128*32]; // 8 KB each
  int t = threadIdx.x;
  int wave = t >> 6, lane = t & 63;
  int wm = wave >> 1, wn = wave & 1;
  int quad = lane >> 4, l16 = lane & 15;
  int bm0 = blockIdx.y*128, bn0 = blockIdx.x*128;

  const unsigned short* gsrc = (wave==0)?Ahg:(wave==1)?Alg:(wave==2)?Bth:Btl;
  unsigned short* lbuf       = (wave==0)?Ah :(wave==1)?Al :(wave==2)?Bh :Bl;
  int sbase = (wave < 2) ? bm0 : bn0;
  int srow = lane >> 2;
  int skg  = (lane & 3) * 8;

  const unsigned short* gp[8];
  #pragma unroll
  for (int i=0;i<8;i++){
    int r = sbase + i*16 + srow;
    if (wave < 2) r = min(r, M-1);   // clamp: dup rows, never OOB
    gp[i] = gsrc + (size_t)r*K + skg;
  }

  f32x4 acc[4][4];
  #pragma unroll
  for (int i=0;i<4;i++)
    #pragma unroll
    for (int j=0;j<4;j++) acc[i][j] = (f32x4){0.f,0.f,0.f,0.f};

  // prologue: DMA iter 0
  #pragma unroll
  for (int i=0;i<8;i++) gload_lds16(gp[i], lbuf + i*512);

  #pragma unroll
  for (int it=0; it<ITERS; ++it){
    __syncthreads();                       // drain DMA(it)

    short8_t afh[4], afl[4], bfh[4], bfl[4];
    #pragma unroll
    for (int mt=0; mt<4; ++mt){
      int row = wm*64 + mt*16 + l16;
      afh[mt] = *(short8_t*)&Ah[row*32 + quad*8];
      afl[mt] = *(short8_t*)&Al[row*32 + quad*8];
    }
    #pragma unroll
    for (int nt=0; nt<4; ++nt){
      int col = wn*64 + nt*16 + l16;
      bfh[nt] = *(short8_t*)&Bh[col*32 + quad*8];
      bfl[nt] = *(short8_t*)&Bl[col*32 + quad*8];
    }
    __syncthreads();                       // all frag reads done; LDS writable

    if (it+1 < ITERS){
      int k0 = (it+1)*32;
      #pragma unroll
      for (int i=0;i<8;i++) gload_lds16(gp[i] + k0, lbuf + i*512);
    }

    #pragma unroll
    for (int mt=0; mt<4; ++mt)
      #pragma unroll
      for (int nt=0; nt<4; ++nt){
        acc[mt][nt] = __builtin_amdgcn_mfma_f32_16x16x32_bf16(afh[mt], bfh[nt], acc[mt][nt], 0,0,0);
        acc[mt][nt] = __builtin_amdgcn_mfma_f32_16x16x32_bf16(afh[mt], bfl[nt], acc[mt][nt], 0,0,0);
        acc[mt][nt] = __builtin_amdgcn_mfma_f32_16x16x32_bf16(afl[mt], bfh[nt], acc[mt][nt], 0,0,0);
      }
  }

  // ---- epilogue 1: fused al via LDS transpose (stride 17 floats) ----
  int head_w = (bn0 >> 6) + wn;
  float cs[4], cd[4];
  #pragma unroll
  for (int nt=0; nt<4; ++nt){
    cs[nt] = a_src[head_w*64 + nt*16 + l16];
    cd[nt] = a_dst[head_w*64 + nt*16 + l16];
  }
  {
    float* fsc = (float*)lbuf;
    int grow = bm0 + wm*64 + lane;
    #pragma unroll
    for (int pass=0; pass<2; ++pass){
      #pragma unroll
      for (int mt=0; mt<4; ++mt)
        #pragma unroll
        for (int r=0; r<4; ++r){
          float p = 0.f;
          #pragma unroll
          for (int nt=0; nt<4; ++nt)
            p += acc[mt][nt][r] * (pass ? cd[nt] : cs[nt]);
          fsc[(mt*16 + quad*4 + r)*17 + l16] = p;
        }
      float s = 0.f;
      #pragma unroll
      for (int j=0; j<16; ++j) s += fsc[lane*17 + j];
      if (grow < M) al[grow*8 + pass*4 + head_w] = s;   // node-major
    }
  }

  // ---- epilogue 2: Cb bf16, group-major [8][NN][32], coalesced dwordx4 ----
  unsigned short* tile = lbuf;
  #pragma unroll
  for (int mt=0; mt<4; ++mt)
    #pragma unroll
    for (int r=0; r<4; ++r){
      int rl = mt*16 + quad*4 + r;
      #pragma unroll
      for (int nt=0; nt<4; ++nt)
        tile[rl*64 + nt*16 + l16] = f2bf(acc[mt][nt][r]);
    }
  int orow = lane >> 3, ocol = (lane & 7) * 8;
  int ch = bn0 + wn*64 + ocol;           // 8 contiguous channels from here
  int g = ch >> 5;                       // group never crosses within the 8
  #pragma unroll
  for (int it=0; it<8; ++it){
    int rl = it*8 + orow;
    int row = bm0 + wm*64 + rl;
    if (row < M){
      uint4 v = *(uint4*)&tile[rl*64 + ocol];
      *(uint4*)(Cb + ((size_t)g*NN + row)*32 + (ch & 31)) = v;
    }
  }
}

// ---------------- GAT aggregation: XCD channel-sliced, exclusive channels ------
// 50000-block grid (R2/R4: FETCH=26MB proven). block = 8 half-waves = 8 nodes,
// ONE 32-channel group (g = bid&7 -> XCD; 3.2 MB hb slice L2-resident; no al
// reads at all - alpha precomputed). Half-wave lane = (c = l32&15 channel-dword,
// r = l32>>4 edge-parity). Gather: 16 lanes x dword = 64 B slice row. Per r-lane
// 4-deep unrolled guarded loads -> 8 edges in flight per node (R0-level MLP).
// Epilogue: 2 shfl_xor(16) + select + 1 swizzle-shfl -> each lane owns ONE
// channel; ELU/pack once per (node,channel). No LDS, no alpha dup (R4/R6 taxes).
template<bool FUSE_W3>
__global__ __launch_bounds__(256) void gat_agg(const unsigned short* __restrict__ hb,
                                               const float* __restrict__ eb4,
                                               const int* __restrict__ indptr, const int* __restrict__ csr,
                                               const float* __restrict__ bias,
                                               unsigned short* __restrict__ outh,
                                               unsigned short* __restrict__ outl,
                                               const float* __restrict__ W3,
                                               float* __restrict__ h3){
  int wave = threadIdx.x >> 6, lane = threadIdx.x & 63;
  int half = lane >> 5, l32 = lane & 31;
  int g    = blockIdx.x & 7;             // channel group -> XCD
  int n    = (blockIdx.x >> 3)*8 + wave*2 + half;   // NN = 6250*8 exactly
  int head = g >> 1;
  int c = l32 & 15, r = l32 >> 4;
  int2 ip = *(const int2*)(indptr + n);
  int base = ip.x, deg = ip.y - ip.x;
  const float* ebh = eb4 + (size_t)head*NETP;
  const unsigned short* hg = hb + (size_t)g*NN*32 + c*2;  // dword = ch {2c,2c+1}

  float a0 = 0.f, a1 = 0.f, es = 0.f;
  for (int jb = r*4; jb < deg; jb += 8){
    #pragma unroll
    for (int k=0; k<4; ++k){
      int j = jb + k;
      if (j < deg){
        int s = __builtin_nontemporal_load(csr + base + j);       // broadcast
        float a = __builtin_nontemporal_load(ebh + base + j);     // broadcast
        unsigned hv = *(const unsigned*)(hg + (size_t)s*32);      // L2 slice, 64B/16 lanes
        es += a;
        a0 += a*bflo(hv);
        a1 += a*bfhi(hv);
      }
    }
  }

  // combine the two edge-parity partials; es becomes the full denominator
  es += __shfl_xor(es, 16);
  a0 += __shfl_xor(a0, 16);
  a1 += __shfl_xor(a1, 16);
  float val = r ? a1 : a0;               // lane (r,c) owns channel 2c+r
  // swizzle so lane l32 owns channel l32 (contiguous stores)
  int src = ((l32 & 1) << 4) | (l32 >> 1);
  val = __shfl(val, src, 32);
  float inv = 1.f/(es + 1e-16f);
  int ch = g*32 + l32;
  float o = val * inv + bias[ch];
  o = o > 0.f ? o : __expf(o) - 1.f;     // elu, once per (node, channel)

  if (FUSE_W3){
    float p = o * W3[ch];
    p += __shfl_xor(p, 1);  p += __shfl_xor(p, 2);
    p += __shfl_xor(p, 4);  p += __shfl_xor(p, 8);
    p += __shfl_xor(p, 16);
    if (l32 == 0) atomicAdd(&h3[n], p);  // 8 group-partials per node
  } else {
    unsigned short hh = f2bf(o);
    unsigned short ll = f2bf(o - bf2f(hh));
    __builtin_nontemporal_store(hh, outh + (size_t)n*FD + ch);  // 64 B/half coalesced
    __builtin_nontemporal_store(ll, outl + (size_t)n*FD + ch);
  }
}

// ---------------- layer 3: scalar GAT on h3, 4 lanes/node, single pass ----------
__global__ __launch_bounds__(256) void gat_agg3(const float* __restrict__ h3, const int* __restrict__ indptr,
                                                const int* __restrict__ csr, const float* __restrict__ asrc,
                                                const float* __restrict__ adst, const float* __restrict__ b3,
                                                float* __restrict__ out){
  int tid = blockIdx.x*blockDim.x + threadIdx.x;
  int n = tid >> 2, sub = tid & 3;
  if (n >= NN) return;
  float as = asrc[0], ad = adst[0];
  float hd = h3[n]*ad;
  int2 ip = *(const int2*)(indptr + n);
  float s = 0.f, w = 0.f;
  for (int e = ip.x + sub; e < ip.y; e += 4){
    float hv = h3[csr[e]];
    float ee = __expf(lrelu(as*hv + hd));
    s += ee; w += ee*hv;
  }
  s += __shfl_xor(s, 1); w += __shfl_xor(w, 1);
  s += __shfl_xor(s, 2); w += __shfl_xor(w, 2);
  if (sub == 0) out[n] = w/(s + 1e-16f) + b3[0];
}

extern "C" void kernel_launch(void* const* d_in, const int* in_sizes, int n_in,
                              void* d_out, int out_size, void* d_ws, size_t ws_size,
                              hipStream_t stream){
  const float* x   = (const float*)d_in[0];
  const int*   ei  = (const int*)d_in[1];
  const float* W1  = (const float*)d_in[2];
  const float* as1 = (const float*)d_in[3];
  const float* ad1 = (const float*)d_in[4];
  const float* b1  = (const float*)d_in[5];
  const float* W2  = (const float*)d_in[6];
  const float* as2 = (const float*)d_in[7];
  const float* ad2 = (const float*)d_in[8];
  const float* b2  = (const float*)d_in[9];
  const float* W3  = (const float*)d_in[10];
  const float* as3 = (const float*)d_in[11];
  const float* ad3 = (const float*)d_in[12];
  const float* b3  = (const float*)d_in[13];
  float* outp = (float*)d_out;

  char* w = (char*)d_ws;
  size_t off = 0;
  auto alloc = [&](size_t bytes)->void*{
    void* p = w + off; off += (bytes + 255) & ~(size_t)255; return p;
  };
  unsigned short* hb  = (unsigned short*)alloc((size_t)NN*FD*2);  // 25.6 MB (Cb, group-major)
  unsigned short* oh  = (unsigned short*)alloc((size_t)NN*FD*2);  // 25.6 MB
  unsigned short* ol  = (unsigned short*)alloc((size_t)NN*FD*2);  // 25.6 MB
  unsigned short* xh  = (unsigned short*)alloc((size_t)NN*128*2); // 12.8 MB
  unsigned short* xl  = (unsigned short*)alloc((size_t)NN*128*2); // 12.8 MB
  float* al    = (float*)alloc((size_t)NN*8*4);                   // 1.6 MB (node-major)
  float* eb4   = (float*)alloc((size_t)4*NETP*4);                 // 11.2 MB (head-major alphas)
  int*   indptr= (int*)alloc((size_t)(NN+1)*4);
  int*   cursor= (int*)alloc((size_t)NN*4);
  int*   csr   = (int*)alloc((size_t)NET*4);                      // 2.8 MB
  int*   csrd  = (int*)alloc((size_t)NET*4);                      // 2.8 MB
  int*   bsums = (int*)alloc(64*4);
  float* h3    = (float*)alloc((size_t)NN*4);
  unsigned short* bt1h = (unsigned short*)alloc((size_t)256*128*2);
  unsigned short* bt1l = (unsigned short*)alloc((size_t)256*128*2);
  unsigned short* bt2h = (unsigned short*)alloc((size_t)256*256*2);
  unsigned short* bt2l = (unsigned short*)alloc((size_t)256*256*2);

  // ---- CSR build + casts (fused init; parallel 2-dispatch scan) ----
  hipMemsetAsync(cursor, 0, (size_t)NN*4, stream);
  hipMemsetAsync(h3, 0, (size_t)NN*4, stream);   // accumulated via atomics in layer-2 agg
  init_fused<<<CAST_BLOCKS + CNT_BLOCKS, 256, 0, stream>>>(x, W1, W2, xh, xl,
                                                           bt1h, bt1l, bt2h, bt2l,
                                                           ei, cursor);
  scan_block<<<NB, 256, 0, stream>>>(cursor, indptr, bsums);
  scan_add<<<(NN+255)/256, 256, 0, stream>>>(indptr, bsums, cursor);
  scatter_csr<<<(NET+255)/256, 256, 0, stream>>>(ei, cursor, csr, csrd);

  dim3 gemm_grid(FD/128, (NN+127)/128);
  int agg_blocks = (NN/8) * 8;     // 6250 node-tiles x 8 channel groups = 50000
  int alpha_blocks = (NET+255)/256;

  // ---- layer 1 ----
  gemm_mfma<128><<<gemm_grid, 256, 0, stream>>>(xh, xl, bt1h, bt1l, hb, as1, ad1, al, NN);
  alpha_k<<<alpha_blocks, 256, 0, stream>>>(csr, csrd, al, eb4);
  gat_agg<false><<<agg_blocks, 256, 0, stream>>>(hb, eb4, indptr, csr, b1, oh, ol, nullptr, nullptr);
  // ---- layer 2 (fused W3 gemv; per-group partials via atomicAdd) ----
  gemm_mfma<256><<<gemm_grid, 256, 0, stream>>>(oh, ol, bt2h, bt2l, hb, as2, ad2, al, NN);
  alpha_k<<<alpha_blocks, 256, 0, stream>>>(csr, csrd, al, eb4);
  gat_agg<true><<<agg_blocks, 256, 0, stream>>>(hb, eb4, indptr, csr, b2, nullptr, nullptr, W3, h3);
  // ---- layer 3 ----
  gat_agg3<<<(NN*4+255)/256, 256, 0, stream>>>(h3, indptr, csr, as3, ad3, b3, outp);
}

// Round 8
// 349.226 us; speedup vs baseline: 1.8646x; 1.8646x over previous
//
#include <hip/hip_runtime.h>
#include <math.h>

#define NN 50000     // nodes
#define NE 650000    // edges (without self loops)
#define NET 700000   // NE + NN self loops
#define NETP (NET + 16)
#define FD 256       // H*C = 4*64
#define NEG 0.2f
#define NB 49        // scan blocks = ceil(NN/1024)

static __device__ __forceinline__ float lrelu(float v){ return v > 0.f ? v : NEG*v; }

// bf16 helpers
static __device__ __forceinline__ unsigned short f2bf(float f){
  union { float f; unsigned u; } v; v.f = f;
  unsigned r = v.u + 0x7fff + ((v.u >> 16) & 1);
  return (unsigned short)(r >> 16);
}
static __device__ __forceinline__ float bf2f(unsigned short h){
  union { unsigned u; float f; } v; v.u = ((unsigned)h) << 16;
  return v.f;
}
static __device__ __forceinline__ float bflo(unsigned u){ return __uint_as_float(u << 16); }
static __device__ __forceinline__ float bfhi(unsigned u){ return __uint_as_float(u & 0xffff0000u); }

// async global->LDS DMA, 16 B per lane, LDS dest = uniform base + lane*16 (m97/m104)
static __device__ __forceinline__ void gload_lds16(const unsigned short* g, unsigned short* l){
  __builtin_amdgcn_global_load_lds(
      (const __attribute__((address_space(1))) unsigned int*)(g),
      (__attribute__((address_space(3))) unsigned int*)(l), 16, 0, 0);
}

typedef __attribute__((ext_vector_type(8))) short short8_t;  // 8 bf16 = 4 VGPR
typedef __attribute__((ext_vector_type(4))) float f32x4;

// ---------------- fused init: cast x/W1/W2 + degree count (disjoint block ranges) ----
#define NX (NN*128)
#define CAST_ELEMS (NX + 128*256 + 256*256)
#define CAST_BLOCKS ((CAST_ELEMS/4 + 255)/256)
#define CNT_BLOCKS ((NET + 255)/256)
__global__ void init_fused(const float* __restrict__ x, const float* __restrict__ W1,
                           const float* __restrict__ W2,
                           unsigned short* __restrict__ xh, unsigned short* __restrict__ xl,
                           unsigned short* __restrict__ bt1h, unsigned short* __restrict__ bt1l,
                           unsigned short* __restrict__ bt2h, unsigned short* __restrict__ bt2l,
                           const int* __restrict__ ei, int* __restrict__ deg){
  int b = blockIdx.x;
  if (b >= CAST_BLOCKS){
    int e = (b - CAST_BLOCKS)*256 + threadIdx.x;
    if (e < NET){
      int d = (e < NE) ? ei[NE + e] : (e - NE);
      atomicAdd(&deg[d], 1);
    }
    return;
  }
  int i = (b*256 + threadIdx.x)*4;
  if (i < NX){
    float4 f = *(const float4*)(x + i);
    ushort4 h, l;
    h.x = f2bf(f.x); l.x = f2bf(f.x - bf2f(h.x));
    h.y = f2bf(f.y); l.y = f2bf(f.y - bf2f(h.y));
    h.z = f2bf(f.z); l.z = f2bf(f.z - bf2f(h.z));
    h.w = f2bf(f.w); l.w = f2bf(f.w - bf2f(h.w));
    *(ushort4*)(xh + i) = h;
    *(ushort4*)(xl + i) = l;
    return;
  }
  int e, K;
  const float* B;
  unsigned short *bh, *bl;
  if (i < NX + 128*256){ e = i - NX; K = 128; B = W1; bh = bt1h; bl = bt1l; }
  else if (i < CAST_ELEMS){ e = i - NX - 128*256; K = 256; B = W2; bh = bt2h; bl = bt2l; }
  else return;
  int k = e >> 8, n = e & 255;
  float4 f = *(const float4*)(B + e);
  #pragma unroll
  for (int j=0;j<4;j++){
    float fv = (j==0)?f.x:(j==1)?f.y:(j==2)?f.z:f.w;
    unsigned short h = f2bf(fv);
    bh[(n+j)*K + k] = h;
    bl[(n+j)*K + k] = f2bf(fv - bf2f(h));
  }
}

// ---------------- CSR scan (parallel: 49 blocks, then 196 blocks) ----------------
__global__ void scan_block(const int* __restrict__ deg, int* __restrict__ excl, int* __restrict__ bsums){
  __shared__ int sh[256];
  int t = threadIdx.x;
  int i0 = blockIdx.x*1024 + t*4;
  int v0 = (i0+0 < NN) ? deg[i0+0] : 0;
  int v1 = (i0+1 < NN) ? deg[i0+1] : 0;
  int v2 = (i0+2 < NN) ? deg[i0+2] : 0;
  int v3 = (i0+3 < NN) ? deg[i0+3] : 0;
  int tot = v0+v1+v2+v3;
  sh[t] = tot;
  __syncthreads();
  for (int off=1; off<256; off<<=1){
    int x = (t>=off) ? sh[t-off] : 0;
    __syncthreads();
    sh[t] += x;
    __syncthreads();
  }
  int base = sh[t] - tot;
  if (i0+0 < NN) excl[i0+0] = base;
  if (i0+1 < NN) excl[i0+1] = base + v0;
  if (i0+2 < NN) excl[i0+2] = base + v0+v1;
  if (i0+3 < NN) excl[i0+3] = base + v0+v1+v2;
  if (t == 255) bsums[blockIdx.x] = sh[255];
}

__global__ void scan_add(int* __restrict__ indptr, const int* __restrict__ bsums, int* __restrict__ cursor){
  __shared__ int boff[64];
  if (threadIdx.x < 64){
    int lane = threadIdx.x;
    int v = (lane < NB) ? bsums[lane] : 0;
    int orig = v;
    for (int off=1; off<64; off<<=1){
      int u = __shfl_up(v, off);
      if (lane >= off) v += u;
    }
    boff[lane] = v - orig;   // exclusive
  }
  __syncthreads();
  int i = blockIdx.x*blockDim.x + threadIdx.x;
  if (i < NN){
    int v = indptr[i] + boff[i>>10];
    indptr[i] = v;
    cursor[i] = v;
  }
  if (i == 0) indptr[NN] = NET;
}

// scatter also records the destination per CSR slot (for edge-parallel alpha_k)
__global__ void scatter_csr(const int* __restrict__ ei, int* __restrict__ cursor,
                            int* __restrict__ csr, int* __restrict__ csrd){
  int e = blockIdx.x*blockDim.x + threadIdx.x;
  if (e >= NET) return;
  int s, d;
  if (e < NE){ s = ei[e]; d = ei[NE+e]; } else { s = e-NE; d = e-NE; }
  int pos = atomicAdd(&cursor[d], 1);
  csr[pos] = s;
  csrd[pos] = d;
}

// ---------------- edge-parallel alpha precompute --------------------------------
// alpha4[pos] = float4 of exp(lrelu(a_src.h[src]+a_dst.h[dst])) for 4 heads,
// EDGE-major so gat_agg reads alphas as a coalesced position-indexed stream.
// Moves the random al[src] gather + 4x exp off the agg's serial chain (R7/R8).
__global__ __launch_bounds__(256) void alpha_k(const int* __restrict__ csr, const int* __restrict__ csrd,
                                               const float* __restrict__ al, float4* __restrict__ alpha4){
  int p = blockIdx.x*256 + threadIdx.x;
  if (p >= NET) return;
  int s = csr[p], d = csrd[p];
  float4 as = *(const float4*)(al + s*8);
  float4 ad = *(const float4*)(al + d*8 + 4);
  float4 e;
  e.x = __expf(lrelu(as.x + ad.x));
  e.y = __expf(lrelu(as.y + ad.y));
  e.z = __expf(lrelu(as.z + ad.z));
  e.w = __expf(lrelu(as.w + ad.w));
  alpha4[p] = e;
}

// ---------------- split-bf16 MFMA GEMM (R0-proven config), pipelined DMA ----
template<int K>
__global__ __launch_bounds__(256, 3) void gemm_mfma(const unsigned short* __restrict__ Ahg,
                                                    const unsigned short* __restrict__ Alg,
                                                    const unsigned short* __restrict__ Bth,
                                                    const unsigned short* __restrict__ Btl,
                                                    unsigned short* __restrict__ Cb,
                                                    const float* __restrict__ a_src,
                                                    const float* __restrict__ a_dst,
                                                    float* __restrict__ al,
                                                    int M){
  constexpr int ITERS = K/32;
  __shared__ unsigned short Ah[128*32], Al[128*32], Bh[128*32], Bl[128*32]; // 8 KB each
  int t = threadIdx.x;
  int wave = t >> 6, lane = t & 63;
  int wm = wave >> 1, wn = wave & 1;
  int quad = lane >> 4, l16 = lane & 15;
  int bm0 = blockIdx.y*128, bn0 = blockIdx.x*128;

  const unsigned short* gsrc = (wave==0)?Ahg:(wave==1)?Alg:(wave==2)?Bth:Btl;
  unsigned short* lbuf       = (wave==0)?Ah :(wave==1)?Al :(wave==2)?Bh :Bl;
  int sbase = (wave < 2) ? bm0 : bn0;
  int srow = lane >> 2;
  int skg  = (lane & 3) * 8;

  const unsigned short* gp[8];
  #pragma unroll
  for (int i=0;i<8;i++){
    int r = sbase + i*16 + srow;
    if (wave < 2) r = min(r, M-1);   // clamp: dup rows, never OOB
    gp[i] = gsrc + (size_t)r*K + skg;
  }

  f32x4 acc[4][4];
  #pragma unroll
  for (int i=0;i<4;i++)
    #pragma unroll
    for (int j=0;j<4;j++) acc[i][j] = (f32x4){0.f,0.f,0.f,0.f};

  // prologue: DMA iter 0
  #pragma unroll
  for (int i=0;i<8;i++) gload_lds16(gp[i], lbuf + i*512);

  #pragma unroll
  for (int it=0; it<ITERS; ++it){
    __syncthreads();                       // drain DMA(it)

    short8_t afh[4], afl[4], bfh[4], bfl[4];
    #pragma unroll
    for (int mt=0; mt<4; ++mt){
      int row = wm*64 + mt*16 + l16;
      afh[mt] = *(short8_t*)&Ah[row*32 + quad*8];
      afl[mt] = *(short8_t*)&Al[row*32 + quad*8];
    }
    #pragma unroll
    for (int nt=0; nt<4; ++nt){
      int col = wn*64 + nt*16 + l16;
      bfh[nt] = *(short8_t*)&Bh[col*32 + quad*8];
      bfl[nt] = *(short8_t*)&Bl[col*32 + quad*8];
    }
    __syncthreads();                       // all frag reads done; LDS writable

    if (it+1 < ITERS){
      int k0 = (it+1)*32;
      #pragma unroll
      for (int i=0;i<8;i++) gload_lds16(gp[i] + k0, lbuf + i*512);
    }

    #pragma unroll
    for (int mt=0; mt<4; ++mt)
      #pragma unroll
      for (int nt=0; nt<4; ++nt){
        acc[mt][nt] = __builtin_amdgcn_mfma_f32_16x16x32_bf16(afh[mt], bfh[nt], acc[mt][nt], 0,0,0);
        acc[mt][nt] = __builtin_amdgcn_mfma_f32_16x16x32_bf16(afh[mt], bfl[nt], acc[mt][nt], 0,0,0);
        acc[mt][nt] = __builtin_amdgcn_mfma_f32_16x16x32_bf16(afl[mt], bfh[nt], acc[mt][nt], 0,0,0);
      }
  }

  // ---- epilogue 1: fused al via LDS transpose (stride 17 floats) ----
  int head_w = (bn0 >> 6) + wn;
  float cs[4], cd[4];
  #pragma unroll
  for (int nt=0; nt<4; ++nt){
    cs[nt] = a_src[head_w*64 + nt*16 + l16];
    cd[nt] = a_dst[head_w*64 + nt*16 + l16];
  }
  {
    float* fsc = (float*)lbuf;
    int grow = bm0 + wm*64 + lane;
    #pragma unroll
    for (int pass=0; pass<2; ++pass){
      #pragma unroll
      for (int mt=0; mt<4; ++mt)
        #pragma unroll
        for (int r=0; r<4; ++r){
          float p = 0.f;
          #pragma unroll
          for (int nt=0; nt<4; ++nt)
            p += acc[mt][nt][r] * (pass ? cd[nt] : cs[nt]);
          fsc[(mt*16 + quad*4 + r)*17 + l16] = p;
        }
      float s = 0.f;
      #pragma unroll
      for (int j=0; j<16; ++j) s += fsc[lane*17 + j];
      if (grow < M) al[grow*8 + pass*4 + head_w] = s;   // node-major
    }
  }

  // ---- epilogue 2: Cb bf16 via per-wave LDS tile + coalesced dwordx4 ----
  unsigned short* tile = lbuf;
  #pragma unroll
  for (int mt=0; mt<4; ++mt)
    #pragma unroll
    for (int r=0; r<4; ++r){
      int rl = mt*16 + quad*4 + r;
      #pragma unroll
      for (int nt=0; nt<4; ++nt)
        tile[rl*64 + nt*16 + l16] = f2bf(acc[mt][nt][r]);
    }
  int orow = lane >> 3, ocol = (lane & 7) * 8;
  #pragma unroll
  for (int it=0; it<8; ++it){
    int rl = it*8 + orow;
    int row = bm0 + wm*64 + rl;
    if (row < M){
      uint4 v = *(uint4*)&tile[rl*64 + ocol];
      *(uint4*)(Cb + (size_t)row*FD + bn0 + wn*64 + ocol) = v;
    }
  }
}

// ---------------- GAT aggregation: R0 structure + precomputed alphas ----------
// one node per 32-lane half, 8-deep uint4 gather MLP (proven optimal shape).
// Alpha front is now a coalesced float4 stream read (alpha4[base+j]) instead of
// random al[src] gather + 4x exp -> shorter serial chain, less VALU.
template<bool FUSE_W3>
__global__ __launch_bounds__(256) void gat_agg(const unsigned short* __restrict__ hb,
                                               const float4* __restrict__ alpha4,
                                               const int* __restrict__ indptr, const int* __restrict__ csr,
                                               const float* __restrict__ bias,
                                               unsigned short* __restrict__ outh,
                                               unsigned short* __restrict__ outl,
                                               const float* __restrict__ W3,
                                               float* __restrict__ h3){
  __shared__ float ebuf[8][128];   // per node: 32 slots x 4 heads
  __shared__ int   sbuf[8][32];    // per node: 32 byte-offsets
  int wave = threadIdx.x >> 6, lane = threadIdx.x & 63;
  int half = lane >> 5, l32 = lane & 31;
  int slot = wave*2 + half;
  int n = blockIdx.x*8 + slot;
  if (n >= NN) return;
  int head8 = l32 >> 3;
  int2 ip = *(const int2*)(indptr + n);
  int base = ip.x, deg = ip.y - ip.x;
  float* eb = &ebuf[slot][0];
  int*   sb = &sbuf[slot][0];
  const char* hp = (const char*)hb + l32*16;

  float acc[8] = {0.f,0.f,0.f,0.f,0.f,0.f,0.f,0.f};
  float4 esum = make_float4(0.f,0.f,0.f,0.f);

  for (int j0 = 0; j0 < deg; j0 += 32){
    int j = j0 + l32;
    float4 e4 = make_float4(0.f,0.f,0.f,0.f);
    int sj = 0;
    if (j < deg){
      sj = csr[base + j];
      e4 = alpha4[base + j];             // coalesced stream (precomputed)
      esum.x += e4.x; esum.y += e4.y; esum.z += e4.z; esum.w += e4.w;
    }
    *(float4*)&eb[l32*4] = e4;
    sb[l32] = sj << 9;                       // byte offset (FD*2 = 512)
    int cnt  = min(32, deg - j0);
    int cpad = (cnt + 7) & ~7;               // pad reads row 0 with alpha 0
    for (int tt = 0; tt < cpad; tt += 8){
      uint4 r[8];
      float v[8];
      #pragma unroll
      for (int q=0; q<8; ++q){
        int o = sb[tt+q];
        v[q] = eb[(tt+q)*4 + head8];
        r[q] = *(const uint4*)(hp + o);
      }
      #pragma unroll
      for (int q=0; q<8; ++q){
        acc[0]+=v[q]*bflo(r[q].x); acc[1]+=v[q]*bfhi(r[q].x);
        acc[2]+=v[q]*bflo(r[q].y); acc[3]+=v[q]*bfhi(r[q].y);
        acc[4]+=v[q]*bflo(r[q].z); acc[5]+=v[q]*bfhi(r[q].z);
        acc[6]+=v[q]*bflo(r[q].w); acc[7]+=v[q]*bfhi(r[q].w);
      }
    }
  }

  for (int off=16; off; off>>=1){
    esum.x += __shfl_xor(esum.x, off);
    esum.y += __shfl_xor(esum.y, off);
    esum.z += __shfl_xor(esum.z, off);
    esum.w += __shfl_xor(esum.w, off);
  }
  float sH = (head8==0)?esum.x:(head8==1)?esum.y:(head8==2)?esum.z:esum.w;
  float inv = 1.f/(sH + 1e-16f);
  int ch0 = l32*8;
  float4 b0 = *(const float4*)(bias + ch0);
  float4 b1 = *(const float4*)(bias + ch0 + 4);
  float o[8];
  o[0]=acc[0]*inv+b0.x; o[1]=acc[1]*inv+b0.y; o[2]=acc[2]*inv+b0.z; o[3]=acc[3]*inv+b0.w;
  o[4]=acc[4]*inv+b1.x; o[5]=acc[5]*inv+b1.y; o[6]=acc[6]*inv+b1.z; o[7]=acc[7]*inv+b1.w;
  #pragma unroll
  for (int i=0;i<8;i++) o[i] = o[i] > 0.f ? o[i] : expm1f(o[i]);   // elu

  if (FUSE_W3){
    float4 w0 = *(const float4*)(W3 + ch0);
    float4 w1 = *(const float4*)(W3 + ch0 + 4);
    float p = o[0]*w0.x + o[1]*w0.y + o[2]*w0.z + o[3]*w0.w
            + o[4]*w1.x + o[5]*w1.y + o[6]*w1.z + o[7]*w1.w;
    #pragma unroll
    for (int off=16; off; off>>=1) p += __shfl_xor(p, off);
    if (l32 == 0) h3[n] = p;
  } else {
    unsigned hi[4], lo[4];
    #pragma unroll
    for (int i=0;i<4;i++){
      unsigned short h0 = f2bf(o[2*i]),   h1 = f2bf(o[2*i+1]);
      unsigned short g0 = f2bf(o[2*i]   - bf2f(h0));
      unsigned short g1 = f2bf(o[2*i+1] - bf2f(h1));
      hi[i] = (unsigned)h0 | ((unsigned)h1 << 16);
      lo[i] = (unsigned)g0 | ((unsigned)g1 << 16);
    }
    *(uint4*)(outh + (size_t)n*FD + ch0) = make_uint4(hi[0],hi[1],hi[2],hi[3]);
    *(uint4*)(outl + (size_t)n*FD + ch0) = make_uint4(lo[0],lo[1],lo[2],lo[3]);
  }
}

// ---------------- layer 3: scalar GAT on h3, 4 lanes/node, single pass ----------
__global__ __launch_bounds__(256) void gat_agg3(const float* __restrict__ h3, const int* __restrict__ indptr,
                                                const int* __restrict__ csr, const float* __restrict__ asrc,
                                                const float* __restrict__ adst, const float* __restrict__ b3,
                                                float* __restrict__ out){
  int tid = blockIdx.x*blockDim.x + threadIdx.x;
  int n = tid >> 2, sub = tid & 3;
  if (n >= NN) return;
  float as = asrc[0], ad = adst[0];
  float hd = h3[n]*ad;
  int2 ip = *(const int2*)(indptr + n);
  float s = 0.f, w = 0.f;
  for (int e = ip.x + sub; e < ip.y; e += 4){
    float hv = h3[csr[e]];
    float ee = __expf(lrelu(as*hv + hd));
    s += ee; w += ee*hv;
  }
  s += __shfl_xor(s, 1); w += __shfl_xor(w, 1);
  s += __shfl_xor(s, 2); w += __shfl_xor(w, 2);
  if (sub == 0) out[n] = w/(s + 1e-16f) + b3[0];
}

extern "C" void kernel_launch(void* const* d_in, const int* in_sizes, int n_in,
                              void* d_out, int out_size, void* d_ws, size_t ws_size,
                              hipStream_t stream){
  const float* x   = (const float*)d_in[0];
  const int*   ei  = (const int*)d_in[1];
  const float* W1  = (const float*)d_in[2];
  const float* as1 = (const float*)d_in[3];
  const float* ad1 = (const float*)d_in[4];
  const float* b1  = (const float*)d_in[5];
  const float* W2  = (const float*)d_in[6];
  const float* as2 = (const float*)d_in[7];
  const float* ad2 = (const float*)d_in[8];
  const float* b2  = (const float*)d_in[9];
  const float* W3  = (const float*)d_in[10];
  const float* as3 = (const float*)d_in[11];
  const float* ad3 = (const float*)d_in[12];
  const float* b3  = (const float*)d_in[13];
  float* outp = (float*)d_out;

  char* w = (char*)d_ws;
  size_t off = 0;
  auto alloc = [&](size_t bytes)->void*{
    void* p = w + off; off += (bytes + 255) & ~(size_t)255; return p;
  };
  unsigned short* hb  = (unsigned short*)alloc((size_t)NN*FD*2);  // 25.6 MB (Cb)
  unsigned short* oh  = (unsigned short*)alloc((size_t)NN*FD*2);  // 25.6 MB
  unsigned short* ol  = (unsigned short*)alloc((size_t)NN*FD*2);  // 25.6 MB
  unsigned short* xh  = (unsigned short*)alloc((size_t)NN*128*2); // 12.8 MB
  unsigned short* xl  = (unsigned short*)alloc((size_t)NN*128*2); // 12.8 MB
  float* al    = (float*)alloc((size_t)NN*8*4);                   // 1.6 MB (node-major)
  float4* alpha4 = (float4*)alloc((size_t)NETP*16);               // 11.2 MB (edge-major)
  int*   indptr= (int*)alloc((size_t)(NN+1)*4);
  int*   cursor= (int*)alloc((size_t)NN*4);
  int*   csr   = (int*)alloc((size_t)NET*4);                      // 2.8 MB
  int*   csrd  = (int*)alloc((size_t)NET*4);                      // 2.8 MB
  int*   bsums = (int*)alloc(64*4);
  float* h3    = (float*)alloc((size_t)NN*4);
  unsigned short* bt1h = (unsigned short*)alloc((size_t)256*128*2);
  unsigned short* bt1l = (unsigned short*)alloc((size_t)256*128*2);
  unsigned short* bt2h = (unsigned short*)alloc((size_t)256*256*2);
  unsigned short* bt2l = (unsigned short*)alloc((size_t)256*256*2);

  // ---- CSR build + casts (fused init; parallel 2-dispatch scan) ----
  hipMemsetAsync(cursor, 0, (size_t)NN*4, stream);
  init_fused<<<CAST_BLOCKS + CNT_BLOCKS, 256, 0, stream>>>(x, W1, W2, xh, xl,
                                                           bt1h, bt1l, bt2h, bt2l,
                                                           ei, cursor);
  scan_block<<<NB, 256, 0, stream>>>(cursor, indptr, bsums);
  scan_add<<<(NN+255)/256, 256, 0, stream>>>(indptr, bsums, cursor);
  scatter_csr<<<(NET+255)/256, 256, 0, stream>>>(ei, cursor, csr, csrd);

  dim3 gemm_grid(FD/128, (NN+127)/128);
  int agg_blocks = (NN+7)/8;
  int alpha_blocks = (NET+255)/256;

  // ---- layer 1 ----
  gemm_mfma<128><<<gemm_grid, 256, 0, stream>>>(xh, xl, bt1h, bt1l, hb, as1, ad1, al, NN);
  alpha_k<<<alpha_blocks, 256, 0, stream>>>(csr, csrd, al, alpha4);
  gat_agg<false><<<agg_blocks, 256, 0, stream>>>(hb, alpha4, indptr, csr, b1, oh, ol, nullptr, nullptr);
  // ---- layer 2 (fused W3 gemv; no oh/ol write) ----
  gemm_mfma<256><<<gemm_grid, 256, 0, stream>>>(oh, ol, bt2h, bt2l, hb, as2, ad2, al, NN);
  alpha_k<<<alpha_blocks, 256, 0, stream>>>(csr, csrd, al, alpha4);
  gat_agg<true><<<agg_blocks, 256, 0, stream>>>(hb, alpha4, indptr, csr, b2, nullptr, nullptr, W3, h3);
  // ---- layer 3 ----
  gat_agg3<<<(NN*4+255)/256, 256, 0, stream>>>(h3, indptr, csr, as3, ad3, b3, outp);
}